// Round 4
// baseline (130.196 us; speedup 1.0000x reference)
//
#include <hip/hip_runtime.h>
#include <hip/hip_bf16.h>

#define BB 2
#define NN 4096
#define DD 1024
#define HH 16
#define RR 4
#define MM 8
#define CC 64
#define DH 64
#define PAD 68

typedef __attribute__((ext_vector_type(8))) short bf16x8;
typedef __attribute__((ext_vector_type(4))) float f32x4;
typedef unsigned long long u64;

__device__ __forceinline__ unsigned short f2bf(float x) {  // RNE via HW cvt
  union { __hip_bfloat16 b; unsigned short u; } cv;
  cv.b = __float2bfloat16(x);
  return cv.u;
}
// swizzled byte address in a [64 rows][128 bytes] LDS tile (conflict-free b128)
__device__ __forceinline__ int swz(int row, int colbyte) {
  return row * 128 + (colbyte ^ ((row & 7) << 4));
}
__device__ __forceinline__ bf16x8 pack8(float4 a, float4 b, float sc) {
  bf16x8 r;
  const float* pa = (const float*)&a;
  const float* pb = (const float*)&b;
#pragma unroll
  for (int j = 0; j < 4; ++j) {
    r[j] = (short)f2bf(pa[j] * sc);
    r[j + 4] = (short)f2bf(pb[j] * sc);
  }
  return r;
}

// ---------------------------------------------------------------------------
// Kernel 1: LSH hash codes (f32 exact -> bucketing identical to reference)
// ---------------------------------------------------------------------------
__global__ __launch_bounds__(256) void k_hash(const float* __restrict__ q,
                                              const float* __restrict__ proj,
                                              int* __restrict__ codes) {
  int blk = blockIdx.x;
  int nc = blk & (CC - 1);
  int h = (blk >> 6) & (HH - 1);
  int b = blk >> 10;
  __shared__ float Qs[64][PAD];
  __shared__ float Ps[DH][MM];
  __shared__ float Ss[64][9];
  int tid = threadIdx.x;
  const float* qbase = q + ((size_t)(b * NN + nc * 64) * DD + h * DH);
  for (int f = tid; f < 1024; f += 256) {
    int row = f >> 4, c4 = f & 15;
    *(float4*)&Qs[row][c4 * 4] = *(const float4*)(qbase + (size_t)row * DD + c4 * 4);
  }
  int nl = tid >> 3, m = tid & 7;
  for (int r = 0; r < RR; ++r) {
    const float* pbase = proj + (size_t)(r * HH + h) * DH * MM;
    for (int f = tid; f < DH * MM / 4; f += 256)
      ((float4*)Ps)[f] = ((const float4*)pbase)[f];
    __syncthreads();
    float s0 = 0.f, s1 = 0.f;
#pragma unroll
    for (int kk = 0; kk < DH; ++kk) {
      float p = Ps[kk][m];
      s0 += Qs[nl][kk] * p;
      s1 += Qs[nl + 32][kk] * p;
    }
    Ss[nl][m] = s0;
    Ss[nl + 32][m] = s1;
    __syncthreads();
    if (tid < 64) {
      float best = Ss[tid][0];
      int bm = 0;
#pragma unroll
      for (int mm = 1; mm < MM; ++mm) {
        float vv = Ss[tid][mm];
        if (vv > best) { best = vv; bm = mm; }  // first-max tie-break (jnp.argmax)
      }
      codes[(size_t)((b * RR + r) * HH + h) * NN + nc * 64 + tid] = bm;
    }
    __syncthreads();
  }
}

// ---------------------------------------------------------------------------
// Kernel 2: stable counting sort via packed-u64 wave scan.
// Valence scaling is a positive-integer monotone map -> argsort invariant.
// ---------------------------------------------------------------------------
__global__ __launch_bounds__(256) void k_sort(const int* __restrict__ codes,
                                              int* __restrict__ idxo) {
  int gblk = blockIdx.x;
  const int* cg = codes + (size_t)gblk * NN;
  int* ig = idxo + (size_t)gblk * NN;
  int tid = threadIdx.x, lane = tid & 63, w = tid >> 6;
  __shared__ u64 wtot[4][2];
  int myc[16];
#pragma unroll
  for (int qd = 0; qd < 4; ++qd) {
    int4 t4 = ((const int4*)(cg + tid * 16))[qd];
    myc[qd * 4 + 0] = t4.x; myc[qd * 4 + 1] = t4.y;
    myc[qd * 4 + 2] = t4.z; myc[qd * 4 + 3] = t4.w;
  }
  u64 c01 = 0, c23 = 0;
#pragma unroll
  for (int i = 0; i < 16; ++i) {
    int k = myc[i];
    u64 one = 1ull << (16 * (k & 3));
    if (k < 4) c01 += one; else c23 += one;
  }
  u64 i01 = c01, i23 = c23;
#pragma unroll
  for (int d = 1; d < 64; d <<= 1) {
    u64 t0 = __shfl_up(i01, d);
    u64 t1 = __shfl_up(i23, d);
    if (lane >= d) { i01 += t0; i23 += t1; }
  }
  if (lane == 63) { wtot[w][0] = i01; wtot[w][1] = i23; }
  __syncthreads();
  u64 base01 = 0, base23 = 0, g01 = 0, g23 = 0;
#pragma unroll
  for (int ww = 0; ww < 4; ++ww) {
    u64 a = wtot[ww][0], bq = wtot[ww][1];
    if (ww < w) { base01 += a; base23 += bq; }
    g01 += a; g23 += bq;
  }
  u64 p01 = g01 + (g01 << 16); p01 += (p01 << 32);
  u64 p23 = g23 + (g23 << 16); p23 += (p23 << 32);
  u64 cb01 = p01 << 16;
  u64 tot01 = (p01 >> 48) & 0xffffull;
  u64 cb23 = (p23 << 16) + tot01 * 0x0001000100010001ull;
  u64 o01 = cb01 + base01 + (i01 - c01);
  u64 o23 = cb23 + base23 + (i23 - c23);
#pragma unroll
  for (int i = 0; i < 16; ++i) {
    int k = myc[i];
    int sh = 16 * (k & 3);
    int off;
    if (k < 4) { off = (int)((o01 >> sh) & 0xffffull); o01 += 1ull << sh; }
    else       { off = (int)((o23 >> sh) & 0xffffull); o23 += 1ull << sh; }
    ig[off] = tid * 16 + i;
  }
}

// ---------------------------------------------------------------------------
// Kernel 3: bucketed attention. Block=(b,h,c), 4 waves, wave w owns rows
// [16w,16w+16). K and Q gathered DIRECT-TO-REGISTER (B-frag wants K rows on
// lanes; per-(t,ks) load = 16 rows x 128B fully coalesced). P via wave-private
// LDS (in-order within wave -> no barrier). V double-buffered in LDS ->
// exactly ONE __syncthreads per r. Full r-unroll lets compiler pipeline:
// V(r+1) loads at iter top, K(r+1) loads after QK^T(r).
// ---------------------------------------------------------------------------
__global__ __launch_bounds__(256, 3) void k_attn(const float* __restrict__ q,
                                                 const float* __restrict__ kmat,
                                                 const float* __restrict__ vmat,
                                                 const int* __restrict__ idxs,
                                                 float* __restrict__ out,
                                                 float* __restrict__ attn_part,
                                                 float* __restrict__ attn_out,
                                                 int atomic_attn) {
  __shared__ __align__(16) char Plds[8192];     // [64 rows][128B], wave w rows 16w..16w+15
  __shared__ __align__(16) char VT[2][8192];    // V^T double buffer
  __shared__ int sidx[RR][64];

  // XCD-aware bijective swizzle: 2048 blocks, 8 XCDs, chunk 256
  int blk = ((int)blockIdx.x & 7) * 256 + ((int)blockIdx.x >> 3);
  int cblk = blk & 63;
  int h = (blk >> 6) & 15;
  int b = blk >> 10;
  int tid = threadIdx.x;
  int lane = tid & 63;
  int w = tid >> 6;
  int g = lane >> 4;
  int cl = lane & 15;
  int e2 = tid & 31, dg = tid >> 5;  // V staging role: rows 2e2,2e2+1, col-octet dg

  sidx[tid >> 6][tid & 63] =
      idxs[(size_t)((b * RR + (tid >> 6)) * HH + h) * NN + cblk * 64 + (tid & 63)];
  __syncthreads();

  const float* kbase = kmat + (size_t)b * NN * DD + h * DH;
  const float* vbase = vmat + (size_t)b * NN * DD + h * DH;

  // ---- Q fragments direct (pre-scaled by 1/8) ----
  const float* qrow = q + (size_t)(b * NN + cblk * 64 + 16 * w + cl) * DD + h * DH;
  bf16x8 qh[2];
#pragma unroll
  for (int ks = 0; ks < 2; ++ks)
    qh[ks] = pack8(*(const float4*)(qrow + 32 * ks + 8 * g),
                   *(const float4*)(qrow + 32 * ks + 8 * g + 4), 0.125f);

  f32x4 acc_o[4];
  float attA[4][4];
#pragma unroll
  for (int t = 0; t < 4; ++t) {
    acc_o[t] = (f32x4){0.f, 0.f, 0.f, 0.f};
#pragma unroll
    for (int i = 0; i < 4; ++i) attA[t][i] = 0.f;
  }

  bf16x8 kf[4][2];
  float4 vtmp[4];

  // prologue: K(0), V(0)
#pragma unroll
  for (int t = 0; t < 4; ++t) {
    const float* kr = kbase + (size_t)sidx[0][16 * t + cl] * DD;
#pragma unroll
    for (int ks = 0; ks < 2; ++ks)
      kf[t][ks] = pack8(*(const float4*)(kr + 32 * ks + 8 * g),
                        *(const float4*)(kr + 32 * ks + 8 * g + 4), 1.f);
  }
  {
    const float* v0 = vbase + (size_t)sidx[0][2 * e2] * DD + 8 * dg;
    const float* v1 = vbase + (size_t)sidx[0][2 * e2 + 1] * DD + 8 * dg;
    vtmp[0] = *(const float4*)v0; vtmp[1] = *(const float4*)(v0 + 4);
    vtmp[2] = *(const float4*)v1; vtmp[3] = *(const float4*)(v1 + 4);
  }
  {
    const float* r0 = (const float*)&vtmp[0];
    const float* r1 = (const float*)&vtmp[2];
#pragma unroll
    for (int j = 0; j < 8; ++j) {
      unsigned pk = (unsigned)f2bf(r0[j]) | ((unsigned)f2bf(r1[j]) << 16);
      *(unsigned*)(VT[0] + swz(8 * dg + j, 4 * e2)) = pk;
    }
  }
  __syncthreads();

#pragma unroll
  for (int r = 0; r < RR; ++r) {
    // ---- issue V(r+1) global loads first (latency hides under whole iter) ----
    if (r < 3) {
      const float* v0 = vbase + (size_t)sidx[r + 1][2 * e2] * DD + 8 * dg;
      const float* v1 = vbase + (size_t)sidx[r + 1][2 * e2 + 1] * DD + 8 * dg;
      vtmp[0] = *(const float4*)v0; vtmp[1] = *(const float4*)(v0 + 4);
      vtmp[2] = *(const float4*)v1; vtmp[3] = *(const float4*)(v1 + 4);
    }
    // ---- QK^T (Q pre-scaled): C-layout row=4g+i, col=cl ----
    f32x4 s4[4];
#pragma unroll
    for (int t = 0; t < 4; ++t) s4[t] = (f32x4){0.f, 0.f, 0.f, 0.f};
    __builtin_amdgcn_s_setprio(1);
#pragma unroll
    for (int t = 0; t < 4; ++t)
#pragma unroll
      for (int ks = 0; ks < 2; ++ks)
        s4[t] = __builtin_amdgcn_mfma_f32_16x16x32_bf16(qh[ks], kf[t][ks], s4[t], 0, 0, 0);
    __builtin_amdgcn_s_setprio(0);
    // ---- issue K(r+1) gather now (used ~600cy later at next QK) ----
    if (r < 3) {
#pragma unroll
      for (int t = 0; t < 4; ++t) {
        const float* kr = kbase + (size_t)sidx[r + 1][16 * t + cl] * DD;
#pragma unroll
        for (int ks = 0; ks < 2; ++ks)
          kf[t][ks] = pack8(*(const float4*)(kr + 32 * ks + 8 * g),
                            *(const float4*)(kr + 32 * ks + 8 * g + 4), 1.f);
      }
    }
    // ---- softmax (row 16w+4g+i spans the 16 lanes of group g) ----
#pragma unroll
    for (int i = 0; i < 4; ++i) {
      float mx = fmaxf(fmaxf(s4[0][i], s4[1][i]), fmaxf(s4[2][i], s4[3][i]));
      mx = fmaxf(mx, __shfl_xor(mx, 1));
      mx = fmaxf(mx, __shfl_xor(mx, 2));
      mx = fmaxf(mx, __shfl_xor(mx, 4));
      mx = fmaxf(mx, __shfl_xor(mx, 8));
      float sm = 0.f;
#pragma unroll
      for (int t = 0; t < 4; ++t) {
        float e = __expf(s4[t][i] - mx);
        s4[t][i] = e;
        sm += e;
      }
      sm += __shfl_xor(sm, 1);
      sm += __shfl_xor(sm, 2);
      sm += __shfl_xor(sm, 4);
      sm += __shfl_xor(sm, 8);
      float inv = __builtin_amdgcn_rcpf(sm);
#pragma unroll
      for (int t = 0; t < 4; ++t) {
        s4[t][i] *= inv;
        attA[t][i] += s4[t][i];
      }
    }
    // ---- P -> wave-private LDS (in-order within wave, no barrier) ----
#pragma unroll
    for (int i = 0; i < 4; ++i) {
      int srow = 16 * w + 4 * g + i;
#pragma unroll
      for (int t = 0; t < 4; ++t)
        *(unsigned short*)(Plds + swz(srow, 2 * (16 * t + cl))) = f2bf(s4[t][i]);
    }
    bf16x8 pa[2];
#pragma unroll
    for (int ks = 0; ks < 2; ++ks)
      pa[ks] = *(const bf16x8*)(Plds + swz(16 * w + cl, ks * 64 + g * 16));
    // ---- PV (reads VT[r&1], staged last iter) ----
    __builtin_amdgcn_s_setprio(1);
#pragma unroll
    for (int t = 0; t < 4; ++t)
#pragma unroll
      for (int ks = 0; ks < 2; ++ks) {
        bf16x8 vt = *(const bf16x8*)(VT[r & 1] + swz(16 * t + cl, ks * 64 + g * 16));
        acc_o[t] = __builtin_amdgcn_mfma_f32_16x16x32_bf16(pa[ks], vt, acc_o[t], 0, 0, 0);
      }
    __builtin_amdgcn_s_setprio(0);
    // ---- stage V(r+1) into other buffer (temps loaded ~1 iter ago) ----
    if (r < 3) {
      const float* r0 = (const float*)&vtmp[0];
      const float* r1 = (const float*)&vtmp[2];
#pragma unroll
      for (int j = 0; j < 8; ++j) {
        unsigned pk = (unsigned)f2bf(r0[j]) | ((unsigned)f2bf(r1[j]) << 16);
        *(unsigned*)(VT[(r + 1) & 1] + swz(8 * dg + j, 4 * e2)) = pk;
      }
      __syncthreads();  // the ONE barrier per r
    }
  }

  // ---- epilogue ----
#pragma unroll
  for (int i = 0; i < 4; ++i) {
    int srow = 16 * w + 4 * g + i;
    size_t obase = (size_t)(b * NN + cblk * 64 + srow) * DD + h * DH;
#pragma unroll
    for (int t = 0; t < 4; ++t)
      out[obase + 16 * t + cl] = acc_o[t][i] * 0.25f;
  }
  if (atomic_attn) {
    const float sc = 1.f / (RR * HH);
#pragma unroll
    for (int i = 0; i < 4; ++i) {
      int srow = 16 * w + 4 * g + i;
#pragma unroll
      for (int t = 0; t < 4; ++t)
        atomicAdd(attn_out + (((size_t)b * CC + cblk) * 64 + srow) * 64 + 16 * t + cl,
                  attA[t][i] * sc);
    }
  } else {
#pragma unroll
    for (int i = 0; i < 4; ++i) {
      int srow = 16 * w + 4 * g + i;
#pragma unroll
      for (int t = 0; t < 4; ++t)
        attn_part[(((size_t)(b * HH + h) * CC + cblk) * 64 + srow) * 64 + 16 * t + cl] =
            attA[t][i];
    }
  }
}

// ---------------------------------------------------------------------------
// Kernel 4: attn_out = (1/(R*H)) * sum_h attn_part
// ---------------------------------------------------------------------------
__global__ __launch_bounds__(256) void k_attn_reduce(const float* __restrict__ part,
                                                     float* __restrict__ attn_out) {
  size_t o = (size_t)blockIdx.x * 256 + threadIdx.x;
  int se = (int)(o & 4095);
  size_t bc = o >> 12;
  int c = (int)(bc & (CC - 1));
  int b = (int)(bc >> 6);
  float s = 0.f;
  const float* p = part + ((size_t)b * HH * CC + c) * 4096 + se;
#pragma unroll
  for (int h = 0; h < HH; ++h) s += p[(size_t)h * CC * 4096];
  attn_out[o] = s * (1.f / (RR * HH));
}

extern "C" void kernel_launch(void* const* d_in, const int* in_sizes, int n_in,
                              void* d_out, int out_size, void* d_ws, size_t ws_size,
                              hipStream_t stream) {
  const float* q = (const float*)d_in[0];
  const float* k = (const float*)d_in[1];
  const float* v = (const float*)d_in[2];
  // d_in[3] (valence), d_in[5] (valence_scale): positive-int monotone code scale
  // -> argsort order invariant -> dead inputs.
  const float* proj = (const float*)d_in[4];
  float* out = (float*)d_out;
  float* attn_out = out + (size_t)BB * NN * DD;

  int* codes = (int*)d_ws;
  int* idxs = codes + (size_t)BB * RR * HH * NN;
  float* attn_part = (float*)(idxs + (size_t)BB * RR * HH * NN);
  size_t need = (size_t)BB * RR * HH * NN * 8 + (size_t)BB * HH * CC * 4096 * 4;
  int atomic_attn = (ws_size < need) ? 1 : 0;
  if (atomic_attn)
    hipMemsetAsync(attn_out, 0, (size_t)BB * CC * 4096 * sizeof(float), stream);

  k_hash<<<BB * HH * CC, 256, 0, stream>>>(q, proj, codes);
  k_sort<<<BB * RR * HH, 256, 0, stream>>>(codes, idxs);
  k_attn<<<BB * HH * CC, 256, 0, stream>>>(q, k, v, idxs, out, attn_part, attn_out, atomic_attn);
  if (!atomic_attn)
    k_attn_reduce<<<BB * CC * 4096 / 256, 256, 0, stream>>>(attn_part, attn_out);
}

// Round 5
// 88.824 us; speedup vs baseline: 1.4658x; 1.4658x over previous
//
#include <hip/hip_runtime.h>
#include <hip/hip_bf16.h>

#define BB 2
#define NN 4096
#define DD 1024
#define HH 16
#define RR 4
#define MM 8
#define CC 64
#define DH 64
#define PAD 68

typedef __attribute__((ext_vector_type(8))) short bf16x8;
typedef __attribute__((ext_vector_type(4))) float f32x4;
typedef unsigned long long u64;

__device__ __forceinline__ unsigned short f2bf(float x) {  // RNE via HW cvt
  union { __hip_bfloat16 b; unsigned short u; } cv;
  cv.b = __float2bfloat16(x);
  return cv.u;
}
// swizzled byte address in a [64 rows][128 bytes] LDS tile (conflict-free b128)
__device__ __forceinline__ int swz(int row, int colbyte) {
  return row * 128 + (colbyte ^ ((row & 7) << 4));
}
__device__ __forceinline__ bf16x8 pack8(float4 a, float4 b, float sc) {
  bf16x8 r;
  const float* pa = (const float*)&a;
  const float* pb = (const float*)&b;
#pragma unroll
  for (int j = 0; j < 4; ++j) {
    r[j] = (short)f2bf(pa[j] * sc);
    r[j + 4] = (short)f2bf(pb[j] * sc);
  }
  return r;
}
// async global->LDS, 16B per lane; LDS dest = base + lane*16 (wave-uniform base)
__device__ __forceinline__ void load_lds16(const void* g, void* l) {
  __builtin_amdgcn_global_load_lds(
      (const __attribute__((address_space(1))) unsigned*)g,
      (__attribute__((address_space(3))) unsigned*)l, 16, 0, 0);
}

// ---------------------------------------------------------------------------
// Kernel 1: LSH hash codes (f32 exact -> bucketing identical to reference)
// ---------------------------------------------------------------------------
__global__ __launch_bounds__(256) void k_hash(const float* __restrict__ q,
                                              const float* __restrict__ proj,
                                              int* __restrict__ codes) {
  int blk = blockIdx.x;
  int nc = blk & (CC - 1);
  int h = (blk >> 6) & (HH - 1);
  int b = blk >> 10;
  __shared__ float Qs[64][PAD];
  __shared__ float Ps[DH][MM];
  __shared__ float Ss[64][9];
  int tid = threadIdx.x;
  const float* qbase = q + ((size_t)(b * NN + nc * 64) * DD + h * DH);
  for (int f = tid; f < 1024; f += 256) {
    int row = f >> 4, c4 = f & 15;
    *(float4*)&Qs[row][c4 * 4] = *(const float4*)(qbase + (size_t)row * DD + c4 * 4);
  }
  int nl = tid >> 3, m = tid & 7;
  for (int r = 0; r < RR; ++r) {
    const float* pbase = proj + (size_t)(r * HH + h) * DH * MM;
    for (int f = tid; f < DH * MM / 4; f += 256)
      ((float4*)Ps)[f] = ((const float4*)pbase)[f];
    __syncthreads();
    float s0 = 0.f, s1 = 0.f;
#pragma unroll
    for (int kk = 0; kk < DH; ++kk) {
      float p = Ps[kk][m];
      s0 += Qs[nl][kk] * p;
      s1 += Qs[nl + 32][kk] * p;
    }
    Ss[nl][m] = s0;
    Ss[nl + 32][m] = s1;
    __syncthreads();
    if (tid < 64) {
      float best = Ss[tid][0];
      int bm = 0;
#pragma unroll
      for (int mm = 1; mm < MM; ++mm) {
        float vv = Ss[tid][mm];
        if (vv > best) { best = vv; bm = mm; }  // first-max tie-break (jnp.argmax)
      }
      codes[(size_t)((b * RR + r) * HH + h) * NN + nc * 64 + tid] = bm;
    }
    __syncthreads();
  }
}

// ---------------------------------------------------------------------------
// Kernel 2: stable counting sort via packed-u64 wave scan.
// Valence scaling is a positive-integer monotone map -> argsort invariant.
// ---------------------------------------------------------------------------
__global__ __launch_bounds__(256) void k_sort(const int* __restrict__ codes,
                                              int* __restrict__ idxo) {
  int gblk = blockIdx.x;
  const int* cg = codes + (size_t)gblk * NN;
  int* ig = idxo + (size_t)gblk * NN;
  int tid = threadIdx.x, lane = tid & 63, w = tid >> 6;
  __shared__ u64 wtot[4][2];
  int myc[16];
#pragma unroll
  for (int qd = 0; qd < 4; ++qd) {
    int4 t4 = ((const int4*)(cg + tid * 16))[qd];
    myc[qd * 4 + 0] = t4.x; myc[qd * 4 + 1] = t4.y;
    myc[qd * 4 + 2] = t4.z; myc[qd * 4 + 3] = t4.w;
  }
  u64 c01 = 0, c23 = 0;
#pragma unroll
  for (int i = 0; i < 16; ++i) {
    int k = myc[i];
    u64 one = 1ull << (16 * (k & 3));
    if (k < 4) c01 += one; else c23 += one;
  }
  u64 i01 = c01, i23 = c23;
#pragma unroll
  for (int d = 1; d < 64; d <<= 1) {
    u64 t0 = __shfl_up(i01, d);
    u64 t1 = __shfl_up(i23, d);
    if (lane >= d) { i01 += t0; i23 += t1; }
  }
  if (lane == 63) { wtot[w][0] = i01; wtot[w][1] = i23; }
  __syncthreads();
  u64 base01 = 0, base23 = 0, g01 = 0, g23 = 0;
#pragma unroll
  for (int ww = 0; ww < 4; ++ww) {
    u64 a = wtot[ww][0], bq = wtot[ww][1];
    if (ww < w) { base01 += a; base23 += bq; }
    g01 += a; g23 += bq;
  }
  u64 p01 = g01 + (g01 << 16); p01 += (p01 << 32);
  u64 p23 = g23 + (g23 << 16); p23 += (p23 << 32);
  u64 cb01 = p01 << 16;
  u64 tot01 = (p01 >> 48) & 0xffffull;
  u64 cb23 = (p23 << 16) + tot01 * 0x0001000100010001ull;
  u64 o01 = cb01 + base01 + (i01 - c01);
  u64 o23 = cb23 + base23 + (i23 - c23);
#pragma unroll
  for (int i = 0; i < 16; ++i) {
    int k = myc[i];
    int sh = 16 * (k & 3);
    int off;
    if (k < 4) { off = (int)((o01 >> sh) & 0xffffull); o01 += 1ull << sh; }
    else       { off = (int)((o23 >> sh) & 0xffffull); o23 += 1ull << sh; }
    ig[off] = tid * 16 + i;
  }
}

// ---------------------------------------------------------------------------
// Kernel 3: bucketed attention. Block=(b,h,c), 4 waves, wave w owns rows
// [16w,16w+16). K gathered via global_load_lds (zero-VGPR async DMA: per-lane
// global src, linear LDS dest) into an f32 tile; converted to bf16 at
// fragment-read time with v_perm_b32 truncation. V reg-transposed (loads
// issued one iteration early). P wave-private LDS (no barrier). 2 barriers/r.
//
// K LDS layout (from dest=base+lane*16): element (row cl, byte col Bc),
// Bc = q*64 + sub*16 + beta  ->  offset t*4096 + q*1024 + sub*256 + cl*16 + beta.
// Frag (t,ks) lane (g,cl): 2x b128 at t*4096 + (2ks+(g>>1))*1024 + (g&1)*512
//                          + cl*16, and +256.
// ---------------------------------------------------------------------------
__global__ __launch_bounds__(256, 4) void k_attn(const float* __restrict__ q,
                                                 const float* __restrict__ kmat,
                                                 const float* __restrict__ vmat,
                                                 const int* __restrict__ idxs,
                                                 float* __restrict__ out,
                                                 float* __restrict__ attn_part,
                                                 float* __restrict__ attn_out,
                                                 int atomic_attn) {
  __shared__ __align__(16) char KL[16384];    // K f32 tile (global_load_lds dest)
  __shared__ __align__(16) char VTl[8192];    // V^T bf16, swizzled
  __shared__ __align__(16) char Plds[8192];   // P bf16, wave-private rows
  __shared__ int sidx[RR][64];

  // XCD-aware bijective swizzle: 2048 blocks, 8 XCDs, chunk 256
  int blk = ((int)blockIdx.x & 7) * 256 + ((int)blockIdx.x >> 3);
  int cblk = blk & 63;
  int h = (blk >> 6) & 15;
  int b = blk >> 10;
  int tid = threadIdx.x;
  int lane = tid & 63;
  int w = tid >> 6;
  int g = lane >> 4;
  int cl = lane & 15;
  int cl2 = lane & 15, sub = lane >> 4;      // K-issue roles
  int e2 = tid & 31, dg = tid >> 5;          // V staging roles

  sidx[tid >> 6][tid & 63] =
      idxs[(size_t)((b * RR + (tid >> 6)) * HH + h) * NN + cblk * 64 + (tid & 63)];
  __syncthreads();

  const char* kbase = (const char*)(kmat + (size_t)b * NN * DD + h * DH);
  const float* vbase = vmat + (size_t)b * NN * DD + h * DH;

  // ---- Q fragments direct (pre-scaled by 1/8, RNE) ----
  const float* qrow = q + (size_t)(b * NN + cblk * 64 + 16 * w + cl) * DD + h * DH;
  bf16x8 qh[2];
#pragma unroll
  for (int ks = 0; ks < 2; ++ks)
    qh[ks] = pack8(*(const float4*)(qrow + 32 * ks + 8 * g),
                   *(const float4*)(qrow + 32 * ks + 8 * g + 4), 0.125f);

  f32x4 acc_o[4];
  float attA[4][4];
#pragma unroll
  for (int t = 0; t < 4; ++t) {
    acc_o[t] = (f32x4){0.f, 0.f, 0.f, 0.f};
#pragma unroll
    for (int i = 0; i < 4; ++i) attA[t][i] = 0.f;
  }

  float4 vtmp[4];
  // ---- prologue: K(0) async chunks (wave w stages tile t=w), V(0) loads+pack ----
  {
    int row = sidx[0][16 * w + cl2];
    const char* gsrc = kbase + (size_t)row * 4096 + sub * 16;
#pragma unroll
    for (int qq = 0; qq < 4; ++qq)
      load_lds16(gsrc + qq * 64, KL + w * 4096 + qq * 1024);
  }
  {
    const float* v0 = vbase + (size_t)sidx[0][2 * e2] * DD + 8 * dg;
    const float* v1 = vbase + (size_t)sidx[0][2 * e2 + 1] * DD + 8 * dg;
    vtmp[0] = *(const float4*)v0; vtmp[1] = *(const float4*)(v0 + 4);
    vtmp[2] = *(const float4*)v1; vtmp[3] = *(const float4*)(v1 + 4);
    const float* r0 = (const float*)&vtmp[0];
    const float* r1 = (const float*)&vtmp[2];
#pragma unroll
    for (int j = 0; j < 8; ++j) {
      unsigned pk = (unsigned)f2bf(r0[j]) | ((unsigned)f2bf(r1[j]) << 16);
      *(unsigned*)(VTl + swz(8 * dg + j, 4 * e2)) = pk;
    }
  }

#pragma unroll
  for (int r = 0; r < RR; ++r) {
    __syncthreads();  // K(r) DMA drained (vmcnt), VT(r) visible

    // ---- issue V(r+1) loads now; pack sits after the end barrier ----
    if (r < 3) {
      const float* v0 = vbase + (size_t)sidx[r + 1][2 * e2] * DD + 8 * dg;
      const float* v1 = vbase + (size_t)sidx[r + 1][2 * e2 + 1] * DD + 8 * dg;
      vtmp[0] = *(const float4*)v0; vtmp[1] = *(const float4*)(v0 + 4);
      vtmp[2] = *(const float4*)v1; vtmp[3] = *(const float4*)(v1 + 4);
    }

    // ---- QK^T from f32 K-LDS: ds_read_b128 x2 + v_perm truncation ----
    f32x4 s4[4];
#pragma unroll
    for (int t = 0; t < 4; ++t) s4[t] = (f32x4){0.f, 0.f, 0.f, 0.f};
    __builtin_amdgcn_s_setprio(1);
#pragma unroll
    for (int t = 0; t < 4; ++t) {
#pragma unroll
      for (int ks = 0; ks < 2; ++ks) {
        int base = t * 4096 + (2 * ks + (g >> 1)) * 1024 + (g & 1) * 512 + cl * 16;
        f32x4 f0 = *(const f32x4*)(KL + base);
        f32x4 f1 = *(const f32x4*)(KL + base + 256);
        const unsigned* u0 = (const unsigned*)&f0;
        const unsigned* u1 = (const unsigned*)&f1;
        union { bf16x8 v; unsigned u[4]; } kb;
        kb.u[0] = __builtin_amdgcn_perm(u0[1], u0[0], 0x07060302);
        kb.u[1] = __builtin_amdgcn_perm(u0[3], u0[2], 0x07060302);
        kb.u[2] = __builtin_amdgcn_perm(u1[1], u1[0], 0x07060302);
        kb.u[3] = __builtin_amdgcn_perm(u1[3], u1[2], 0x07060302);
        s4[t] = __builtin_amdgcn_mfma_f32_16x16x32_bf16(qh[ks], kb.v, s4[t], 0, 0, 0);
      }
    }
    __builtin_amdgcn_s_setprio(0);

    // ---- softmax (row 16w+4g+i spans the 16 lanes of group g) ----
#pragma unroll
    for (int i = 0; i < 4; ++i) {
      float mx = fmaxf(fmaxf(s4[0][i], s4[1][i]), fmaxf(s4[2][i], s4[3][i]));
      mx = fmaxf(mx, __shfl_xor(mx, 1));
      mx = fmaxf(mx, __shfl_xor(mx, 2));
      mx = fmaxf(mx, __shfl_xor(mx, 4));
      mx = fmaxf(mx, __shfl_xor(mx, 8));
      float sm = 0.f;
#pragma unroll
      for (int t = 0; t < 4; ++t) {
        float e = __expf(s4[t][i] - mx);
        s4[t][i] = e;
        sm += e;
      }
      sm += __shfl_xor(sm, 1);
      sm += __shfl_xor(sm, 2);
      sm += __shfl_xor(sm, 4);
      sm += __shfl_xor(sm, 8);
      float inv = __builtin_amdgcn_rcpf(sm);
#pragma unroll
      for (int t = 0; t < 4; ++t) {
        s4[t][i] *= inv;
        attA[t][i] += s4[t][i];
      }
    }
    // ---- P -> wave-private LDS (in-order within wave, no barrier) ----
#pragma unroll
    for (int i = 0; i < 4; ++i) {
      int srow = 16 * w + 4 * g + i;
#pragma unroll
      for (int t = 0; t < 4; ++t)
        *(unsigned short*)(Plds + swz(srow, 2 * (16 * t + cl))) = f2bf(s4[t][i]);
    }
    bf16x8 pa[2];
#pragma unroll
    for (int ks = 0; ks < 2; ++ks)
      pa[ks] = *(const bf16x8*)(Plds + swz(16 * w + cl, ks * 64 + g * 16));
    // ---- PV ----
    __builtin_amdgcn_s_setprio(1);
#pragma unroll
    for (int t = 0; t < 4; ++t)
#pragma unroll
      for (int ks = 0; ks < 2; ++ks) {
        bf16x8 vt = *(const bf16x8*)(VTl + swz(16 * t + cl, ks * 64 + g * 16));
        acc_o[t] = __builtin_amdgcn_mfma_f32_16x16x32_bf16(pa[ks], vt, acc_o[t], 0, 0, 0);
      }
    __builtin_amdgcn_s_setprio(0);

    __syncthreads();  // all waves done reading KL(r)/VT(r)

    if (r < 3) {
      // ---- issue K(r+1) DMA (zero-VGPR, drains at next top barrier) ----
      int row = sidx[r + 1][16 * w + cl2];
      const char* gsrc = kbase + (size_t)row * 4096 + sub * 16;
#pragma unroll
      for (int qq = 0; qq < 4; ++qq)
        load_lds16(gsrc + qq * 64, KL + w * 4096 + qq * 1024);
      // ---- pack V(r+1) (vtmp loaded ~a full phase ago) ----
      const float* r0 = (const float*)&vtmp[0];
      const float* r1 = (const float*)&vtmp[2];
#pragma unroll
      for (int j = 0; j < 8; ++j) {
        unsigned pk = (unsigned)f2bf(r0[j]) | ((unsigned)f2bf(r1[j]) << 16);
        *(unsigned*)(VTl + swz(8 * dg + j, 4 * e2)) = pk;
      }
    }
  }

  // ---- epilogue ----
#pragma unroll
  for (int i = 0; i < 4; ++i) {
    int srow = 16 * w + 4 * g + i;
    size_t obase = (size_t)(b * NN + cblk * 64 + srow) * DD + h * DH;
#pragma unroll
    for (int t = 0; t < 4; ++t)
      out[obase + 16 * t + cl] = acc_o[t][i] * 0.25f;
  }
  if (atomic_attn) {
    const float sc = 1.f / (RR * HH);
#pragma unroll
    for (int i = 0; i < 4; ++i) {
      int srow = 16 * w + 4 * g + i;
#pragma unroll
      for (int t = 0; t < 4; ++t)
        atomicAdd(attn_out + (((size_t)b * CC + cblk) * 64 + srow) * 64 + 16 * t + cl,
                  attA[t][i] * sc);
    }
  } else {
#pragma unroll
    for (int i = 0; i < 4; ++i) {
      int srow = 16 * w + 4 * g + i;
#pragma unroll
      for (int t = 0; t < 4; ++t)
        attn_part[(((size_t)(b * HH + h) * CC + cblk) * 64 + srow) * 64 + 16 * t + cl] =
            attA[t][i];
    }
  }
}

// ---------------------------------------------------------------------------
// Kernel 4: attn_out = (1/(R*H)) * sum_h attn_part
// ---------------------------------------------------------------------------
__global__ __launch_bounds__(256) void k_attn_reduce(const float* __restrict__ part,
                                                     float* __restrict__ attn_out) {
  size_t o = (size_t)blockIdx.x * 256 + threadIdx.x;
  int se = (int)(o & 4095);
  size_t bc = o >> 12;
  int c = (int)(bc & (CC - 1));
  int b = (int)(bc >> 6);
  float s = 0.f;
  const float* p = part + ((size_t)b * HH * CC + c) * 4096 + se;
#pragma unroll
  for (int h = 0; h < HH; ++h) s += p[(size_t)h * CC * 4096];
  attn_out[o] = s * (1.f / (RR * HH));
}

extern "C" void kernel_launch(void* const* d_in, const int* in_sizes, int n_in,
                              void* d_out, int out_size, void* d_ws, size_t ws_size,
                              hipStream_t stream) {
  const float* q = (const float*)d_in[0];
  const float* k = (const float*)d_in[1];
  const float* v = (const float*)d_in[2];
  // d_in[3] (valence), d_in[5] (valence_scale): positive-int monotone code scale
  // -> argsort order invariant -> dead inputs.
  const float* proj = (const float*)d_in[4];
  float* out = (float*)d_out;
  float* attn_out = out + (size_t)BB * NN * DD;

  int* codes = (int*)d_ws;
  int* idxs = codes + (size_t)BB * RR * HH * NN;
  float* attn_part = (float*)(idxs + (size_t)BB * RR * HH * NN);
  size_t need = (size_t)BB * RR * HH * NN * 8 + (size_t)BB * HH * CC * 4096 * 4;
  int atomic_attn = (ws_size < need) ? 1 : 0;
  if (atomic_attn)
    hipMemsetAsync(attn_out, 0, (size_t)BB * CC * 4096 * sizeof(float), stream);

  k_hash<<<BB * HH * CC, 256, 0, stream>>>(q, proj, codes);
  k_sort<<<BB * RR * HH, 256, 0, stream>>>(codes, idxs);
  k_attn<<<BB * HH * CC, 256, 0, stream>>>(q, k, v, idxs, out, attn_part, attn_out, atomic_attn);
  if (!atomic_attn)
    k_attn_reduce<<<BB * CC * 4096 / 256, 256, 0, stream>>>(attn_part, attn_out);
}